// Round 5
// baseline (201.557 us; speedup 1.0000x reference)
//
#include <hip/hip_runtime.h>

#define NCAM 4
#define C 336
#define H 96
#define W 176
#define D 6
#define HB 240
#define WB 120
#define HW (H * W)        // 16896
#define WBPB 60           // wb per block (2 parts)
#define NWP 2

static __device__ __forceinline__ unsigned short f2bf(float f) {
    unsigned u = __float_as_uint(f);
    unsigned r = (u + 0x7fffu + ((u >> 16) & 1u)) >> 16;   // RNE
    return (unsigned short)r;
}

// ---------------------------------------------------------------------------
// Pass 1: feat[cam][c][h*w] (f32) -> tfeat[cam][h*w][c] (bf16)
// ~26 us, near its 136 MB roofline. Unchanged.
// ---------------------------------------------------------------------------
__global__ __launch_bounds__(256)
void vp_transpose_bf16(const float* __restrict__ in,
                       unsigned short* __restrict__ out) {
    __shared__ float tile[64][33];
    const int cam = blockIdx.z;
    const int hw0 = blockIdx.x * 64;
    const int c0  = blockIdx.y * 32;
    const int tid = threadIdx.x;

    const int hwq = tid & 15;
    const int cl  = tid >> 4;
    const float* src = in + (size_t)cam * C * HW + hw0 + hwq * 4;
#pragma unroll
    for (int cc = 0; cc < 2; ++cc) {
        const int c = c0 + cl + cc * 16;
        if (c < C) {
            const float4 v = *(const float4*)(src + (size_t)c * HW);
            tile[hwq * 4 + 0][cl + cc * 16] = v.x;
            tile[hwq * 4 + 1][cl + cc * 16] = v.y;
            tile[hwq * 4 + 2][cl + cc * 16] = v.z;
            tile[hwq * 4 + 3][cl + cc * 16] = v.w;
        }
    }
    __syncthreads();

    const int hw  = tid >> 2;
    const int oct = tid & 3;
    const int cs  = c0 + oct * 8;
    if (cs < C) {
        uint4 r;
        unsigned* pr = (unsigned*)&r;
#pragma unroll
        for (int k = 0; k < 4; ++k) {
            unsigned lo = f2bf(tile[hw][oct * 8 + 2 * k]);
            unsigned hi = f2bf(tile[hw][oct * 8 + 2 * k + 1]);
            pr[k] = lo | (hi << 16);
        }
        *(uint4*)(out + (size_t)cam * HW * C + (size_t)(hw0 + hw) * C + cs) = r;
    }
}

// ---------------------------------------------------------------------------
// Pass 2: one block per (d, hb, wbpart): 336 c x 60 wb, cparts looped inside.
// KEY CHANGE vs R4: __launch_bounds__(256, 8) -> 8 blocks/CU (was capped at
// 4 = 50% occupancy; R2/R4 both measured at that cap). VGPR must stay <= 64:
// loads batched one cam at a time (4 uint4 = 16 regs live) so the allocator
// fits the cap without scratch. LDS-staged full-row store sweeps retained
// (proven exact 227 MB write traffic).
// ---------------------------------------------------------------------------
__global__ __launch_bounds__(256, 8)
void vp_gather_bf16(const unsigned short* __restrict__ tfeat,
                    const int* __restrict__ pu, const int* __restrict__ pv,
                    const int* __restrict__ pvalid,
                    const float* __restrict__ pdens,
                    float* __restrict__ out) {
    __shared__ int   s_off[NCAM][WBPB];
    __shared__ float s_wgt[NCAM][WBPB];
    __shared__ float s_acc[56][61];

    const int d   = blockIdx.x / HB;
    const int hb  = blockIdx.x % HB;
    const int wb0 = blockIdx.y * WBPB;
    const int tid = threadIdx.x;

    if (tid < NCAM * WBPB) {
        const int cam = tid / WBPB, wbl = tid % WBPB;
        const size_t pidx = ((size_t)(cam * D + d) * HB + hb) * WB + wb0 + wbl;
        s_wgt[cam][wbl] = pvalid[pidx] ? pdens[pidx] : 0.0f;
        s_off[cam][wbl] = cam * (HW * C) + (pv[pidx] * W + pu[pidx]) * C;
    }
    __syncthreads();

    const int wave  = tid >> 6;
    const int lane  = tid & 63;
    const int cq    = lane & 15;               // active < 14
    const int wbsub = lane >> 4;               // 0..3
    const bool cact = (cq < 14);
    const int coff  = (cact ? cq : 13) * 8;    // element offset of c-octet

    int wbc[4];
#pragma unroll
    for (int wbi = 0; wbi < 4; ++wbi) {
        const int wbl = wbsub + 4 * wbi;       // 0..15, active < 15
        wbc[wbi] = wave * 15 + (wbl < 15 ? wbl : 14);
    }

#pragma unroll
    for (int cp = 0; cp < 3; ++cp) {
        float acc[4][8];
#pragma unroll
        for (int i = 0; i < 4; ++i)
#pragma unroll
            for (int j = 0; j < 8; ++j) acc[i][j] = 0.0f;

        // one cam at a time: 4 uint4 (16 VGPR) in flight + 32 acc fits 64-cap
#pragma unroll
        for (int cam = 0; cam < NCAM; ++cam) {
            uint4 q[4];
#pragma unroll
            for (int wbi = 0; wbi < 4; ++wbi)
                q[wbi] = *(const uint4*)(tfeat +
                    (unsigned)(s_off[cam][wbc[wbi]] + coff + cp * 112));
#pragma unroll
            for (int wbi = 0; wbi < 4; ++wbi) {
                const float w = s_wgt[cam][wbc[wbi]];
                const uint4 v = q[wbi];
                acc[wbi][0] += w * __uint_as_float(v.x << 16);
                acc[wbi][1] += w * __uint_as_float(v.x & 0xffff0000u);
                acc[wbi][2] += w * __uint_as_float(v.y << 16);
                acc[wbi][3] += w * __uint_as_float(v.y & 0xffff0000u);
                acc[wbi][4] += w * __uint_as_float(v.z << 16);
                acc[wbi][5] += w * __uint_as_float(v.z & 0xffff0000u);
                acc[wbi][6] += w * __uint_as_float(v.w << 16);
                acc[wbi][7] += w * __uint_as_float(v.w & 0xffff0000u);
            }
        }

        // dump + store, two halves of 56 c-rows
#pragma unroll
        for (int half = 0; half < 2; ++half) {
            if (cact && cq >= half * 7 && cq < half * 7 + 7) {
                const int rbase = (cq - half * 7) * 8;
#pragma unroll
                for (int wbi = 0; wbi < 4; ++wbi) {
                    const int wbl = wbsub + 4 * wbi;
                    if (wbl < 15) {
#pragma unroll
                        for (int j = 0; j < 8; ++j)
                            s_acc[rbase + j][wave * 15 + wbl] = acc[wbi][j];
                    }
                }
            }
            __syncthreads();

            const int wp = tid & 31;           // active < 30
            const int rb = tid >> 5;           // 0..7
            if (wp < 30) {
#pragma unroll
                for (int k = 0; k < 7; ++k) {
                    const int r = rb + 8 * k;
                    const int c = cp * 112 + half * 56 + r;
                    float2 v;
                    v.x = s_acc[r][wp * 2 + 0];
                    v.y = s_acc[r][wp * 2 + 1];
                    *(float2*)(out + (((size_t)d * C + c) * HB + hb) * WB +
                               wb0 + wp * 2) = v;
                }
            }
            __syncthreads();
        }
    }
}

extern "C" void kernel_launch(void* const* d_in, const int* in_sizes, int n_in,
                              void* d_out, int out_size, void* d_ws,
                              size_t ws_size, hipStream_t stream) {
    const float* feat  = (const float*)d_in[0];
    const int* pu      = (const int*)d_in[1];
    const int* pv      = (const int*)d_in[2];
    const int* pvalid  = (const int*)d_in[3];
    const float* pdens = (const float*)d_in[4];
    float* out         = (float*)d_out;

    unsigned short* tfeat = (unsigned short*)d_ws;   // 45.4 MB

    dim3 tgrid(HW / 64, (C + 31) / 32, NCAM);
    vp_transpose_bf16<<<tgrid, 256, 0, stream>>>(feat, tfeat);

    dim3 ggrid(D * HB, NWP);
    vp_gather_bf16<<<ggrid, 256, 0, stream>>>(tfeat, pu, pv, pvalid, pdens,
                                              out);
}

// Round 6
// 175.117 us; speedup vs baseline: 1.1510x; 1.1510x over previous
//
#include <hip/hip_runtime.h>

#define NCAM 4
#define C 336
#define H 96
#define W 176
#define D 6
#define HB 240
#define WB 120
#define HW (H * W)        // 16896

typedef unsigned u32x4 __attribute__((ext_vector_type(4)));

static __device__ __forceinline__ unsigned short f2bf(float f) {
    unsigned u = __float_as_uint(f);
    unsigned r = (u + 0x7fffu + ((u >> 16) & 1u)) >> 16;   // RNE
    return (unsigned short)r;
}

// ---------------------------------------------------------------------------
// Pass 1: feat[cam][c][h*w] (f32) -> tfeat[cam][h*w][c] (bf16). ~26 us.
// ---------------------------------------------------------------------------
__global__ __launch_bounds__(256)
void vp_transpose_bf16(const float* __restrict__ in,
                       unsigned short* __restrict__ out) {
    __shared__ float tile[64][33];
    const int cam = blockIdx.z;
    const int hw0 = blockIdx.x * 64;
    const int c0  = blockIdx.y * 32;
    const int tid = threadIdx.x;

    const int hwq = tid & 15;
    const int cl  = tid >> 4;
    const float* src = in + (size_t)cam * C * HW + hw0 + hwq * 4;
#pragma unroll
    for (int cc = 0; cc < 2; ++cc) {
        const int c = c0 + cl + cc * 16;
        if (c < C) {
            const float4 v = *(const float4*)(src + (size_t)c * HW);
            tile[hwq * 4 + 0][cl + cc * 16] = v.x;
            tile[hwq * 4 + 1][cl + cc * 16] = v.y;
            tile[hwq * 4 + 2][cl + cc * 16] = v.z;
            tile[hwq * 4 + 3][cl + cc * 16] = v.w;
        }
    }
    __syncthreads();

    const int hw  = tid >> 2;
    const int oct = tid & 3;
    const int cs  = c0 + oct * 8;
    if (cs < C) {
        uint4 r;
        unsigned* pr = (unsigned*)&r;
#pragma unroll
        for (int k = 0; k < 4; ++k) {
            unsigned lo = f2bf(tile[hw][oct * 8 + 2 * k]);
            unsigned hi = f2bf(tile[hw][oct * 8 + 2 * k + 1]);
            pr[k] = lo | (hi << 16);
        }
        *(uint4*)(out + (size_t)cam * HW * C + (size_t)(hw0 + hw) * C + cs) = r;
    }
}

// ---------------------------------------------------------------------------
// Pass 2: one 512-thread block per (d, hb): 336 c x full 120 wb.
// 8 waves x 15 wb; 3 cparts of 112 c looped inside. Per cpart each wave
// issues 16 asm global_load_dwordx4 (forced 256 B/lane in flight), consumes
// per-cam with counted vmcnt (never drains to 0 across the store phase:
// next cpart's loads are issued BEFORE the LDS dump/store sweeps, which use
// raw s_barrier + lgkmcnt(0) only). Full-row sweeps keep writes exact.
// ---------------------------------------------------------------------------
#define LOADQ(dst, off, TF) \
    asm volatile("global_load_dwordx4 %0, %1, %2" \
                 : "=v"(dst) : "v"(off), "s"(TF))

#define VMWAIT(N) \
    do { asm volatile("s_waitcnt vmcnt(" #N ")" ::: "memory"); \
         __builtin_amdgcn_sched_barrier(0); } while (0)

#define LBAR() \
    do { asm volatile("s_waitcnt lgkmcnt(0)" ::: "memory"); \
         __builtin_amdgcn_sched_barrier(0); \
         __builtin_amdgcn_s_barrier(); } while (0)

#define ISSUE16() \
    do { \
        _Pragma("unroll") \
        for (int cam = 0; cam < 4; ++cam) { \
            _Pragma("unroll") \
            for (int wbi = 0; wbi < 4; ++wbi) { \
                LOADQ(q[cam][wbi], voff[cam][wbi], tfeat); \
                voff[cam][wbi] += 224u; \
            } \
        } \
    } while (0)

#define FMACAM(cam, NW, OP) \
    do { \
        VMWAIT(NW); \
        _Pragma("unroll") \
        for (int wbi = 0; wbi < 4; ++wbi) { \
            const float w = s_wgt[cam][wbc[wbi]]; \
            const u32x4 v = q[cam][wbi]; \
            acc[wbi][0] OP w * __uint_as_float(v[0] << 16); \
            acc[wbi][1] OP w * __uint_as_float(v[0] & 0xffff0000u); \
            acc[wbi][2] OP w * __uint_as_float(v[1] << 16); \
            acc[wbi][3] OP w * __uint_as_float(v[1] & 0xffff0000u); \
            acc[wbi][4] OP w * __uint_as_float(v[2] << 16); \
            acc[wbi][5] OP w * __uint_as_float(v[2] & 0xffff0000u); \
            acc[wbi][6] OP w * __uint_as_float(v[3] << 16); \
            acc[wbi][7] OP w * __uint_as_float(v[3] & 0xffff0000u); \
        } \
    } while (0)

__global__ __launch_bounds__(512, 2)
void vp_gather_bf16(const unsigned short* __restrict__ tfeat,
                    const int* __restrict__ pu, const int* __restrict__ pv,
                    const int* __restrict__ pvalid,
                    const float* __restrict__ pdens,
                    float* __restrict__ out) {
    __shared__ int   s_off[NCAM][WB];
    __shared__ float s_wgt[NCAM][WB];
    __shared__ float s_acc[56][121];

    const int d   = blockIdx.x / HB;
    const int hb  = blockIdx.x % HB;
    const int tid = threadIdx.x;

    if (tid < NCAM * WB) {
        const int cam = tid / WB, wb = tid % WB;
        const size_t pidx = ((size_t)(cam * D + d) * HB + hb) * WB + wb;
        s_wgt[cam][wb] = pvalid[pidx] ? pdens[pidx] : 0.0f;
        s_off[cam][wb] = cam * (HW * C) + (pv[pidx] * W + pu[pidx]) * C;
    }
    __syncthreads();

    const int wave  = tid >> 6;                // 0..7, owns wb [wave*15, +15)
    const int lane  = tid & 63;
    const int cq    = lane & 15;               // active < 14
    const int wbsub = lane >> 4;               // 0..3
    const bool cact = (cq < 14);
    const int coff  = (cact ? cq : 13) * 8;    // c-octet element offset

    int wbc[4];
#pragma unroll
    for (int wbi = 0; wbi < 4; ++wbi) {
        const int wbl = wbsub + 4 * wbi;       // active < 15
        wbc[wbi] = wave * 15 + (wbl < 15 ? wbl : 14);
    }

    unsigned voff[4][4];                        // byte offsets into tfeat
#pragma unroll
    for (int cam = 0; cam < 4; ++cam)
#pragma unroll
        for (int wbi = 0; wbi < 4; ++wbi)
            voff[cam][wbi] = (unsigned)(s_off[cam][wbc[wbi]] + coff) * 2u;

    u32x4 q[4][4];
    float acc[4][8];

    // dump acc -> LDS and sweep-store, two halves of 56 c-rows each.
    auto dumpstore = [&](int cp) {
#pragma unroll
        for (int half = 0; half < 2; ++half) {
            if (cact && cq >= half * 7 && cq < half * 7 + 7) {
                const int rbase = (cq - half * 7) * 8;
#pragma unroll
                for (int wbi = 0; wbi < 4; ++wbi) {
                    const int wbl = wbsub + 4 * wbi;
                    if (wbl < 15) {
#pragma unroll
                        for (int j = 0; j < 8; ++j)
                            s_acc[rbase + j][wave * 15 + wbl] = acc[wbi][j];
                    }
                }
            }
            LBAR();
            const int wp = tid & 63;           // active < 60
            const int rb = tid >> 6;           // 0..7
            if (wp < 60) {
#pragma unroll
                for (int k = 0; k < 7; ++k) {
                    const int r = rb + 8 * k;
                    const int c = cp * 112 + half * 56 + r;
                    float2 v;
                    v.x = s_acc[r][wp * 2 + 0];
                    v.y = s_acc[r][wp * 2 + 1];
                    *(float2*)(out + (((size_t)d * C + c) * HB + hb) * WB +
                               wp * 2) = v;
                }
            }
            LBAR();
        }
    };

    ISSUE16();                                  // cp0 loads in flight
    // ---- cp0: no prior stores outstanding -> waits 12/8/4/0
    FMACAM(0, 12, =);
    FMACAM(1, 8, +=);
    FMACAM(2, 4, +=);
    FMACAM(3, 0, +=);
    ISSUE16();                                  // cp1 loads (before stores)
    dumpstore(0);                               // 14 stores join the queue
    // ---- cp1: 16 loads oldest, 14 stores newer -> waits 26/22/18/14
    FMACAM(0, 26, =);
    FMACAM(1, 22, +=);
    FMACAM(2, 18, +=);
    FMACAM(3, 14, +=);
    ISSUE16();                                  // cp2 loads
    dumpstore(1);
    // ---- cp2
    FMACAM(0, 26, =);
    FMACAM(1, 22, +=);
    FMACAM(2, 18, +=);
    FMACAM(3, 14, +=);
    dumpstore(2);
}

extern "C" void kernel_launch(void* const* d_in, const int* in_sizes, int n_in,
                              void* d_out, int out_size, void* d_ws,
                              size_t ws_size, hipStream_t stream) {
    const float* feat  = (const float*)d_in[0];
    const int* pu      = (const int*)d_in[1];
    const int* pv      = (const int*)d_in[2];
    const int* pvalid  = (const int*)d_in[3];
    const float* pdens = (const float*)d_in[4];
    float* out         = (float*)d_out;

    unsigned short* tfeat = (unsigned short*)d_ws;   // 45.4 MB

    dim3 tgrid(HW / 64, (C + 31) / 32, NCAM);
    vp_transpose_bf16<<<tgrid, 256, 0, stream>>>(feat, tfeat);

    vp_gather_bf16<<<D * HB, 512, 0, stream>>>(tfeat, pu, pv, pvalid, pdens,
                                               out);
}

// Round 7
// 170.862 us; speedup vs baseline: 1.1797x; 1.0249x over previous
//
#include <hip/hip_runtime.h>

#define NCAM 4
#define C 336
#define H 96
#define W 176
#define D 6
#define HB 240
#define WB 120
#define HW (H * W)        // 16896

typedef unsigned u32x4 __attribute__((ext_vector_type(4)));

static __device__ __forceinline__ unsigned short f2bf(float f) {
    unsigned u = __float_as_uint(f);
    unsigned r = (u + 0x7fffu + ((u >> 16) & 1u)) >> 16;   // RNE
    return (unsigned short)r;
}

// ---------------------------------------------------------------------------
// Pass 1: feat[cam][c][h*w] (f32) -> tfeat[cam][h*w][c] (bf16). ~26 us.
// ---------------------------------------------------------------------------
__global__ __launch_bounds__(256)
void vp_transpose_bf16(const float* __restrict__ in,
                       unsigned short* __restrict__ out) {
    __shared__ float tile[64][33];
    const int cam = blockIdx.z;
    const int hw0 = blockIdx.x * 64;
    const int c0  = blockIdx.y * 32;
    const int tid = threadIdx.x;

    const int hwq = tid & 15;
    const int cl  = tid >> 4;
    const float* src = in + (size_t)cam * C * HW + hw0 + hwq * 4;
#pragma unroll
    for (int cc = 0; cc < 2; ++cc) {
        const int c = c0 + cl + cc * 16;
        if (c < C) {
            const float4 v = *(const float4*)(src + (size_t)c * HW);
            tile[hwq * 4 + 0][cl + cc * 16] = v.x;
            tile[hwq * 4 + 1][cl + cc * 16] = v.y;
            tile[hwq * 4 + 2][cl + cc * 16] = v.z;
            tile[hwq * 4 + 3][cl + cc * 16] = v.w;
        }
    }
    __syncthreads();

    const int hw  = tid >> 2;
    const int oct = tid & 3;
    const int cs  = c0 + oct * 8;
    if (cs < C) {
        uint4 r;
        unsigned* pr = (unsigned*)&r;
#pragma unroll
        for (int k = 0; k < 4; ++k) {
            unsigned lo = f2bf(tile[hw][oct * 8 + 2 * k]);
            unsigned hi = f2bf(tile[hw][oct * 8 + 2 * k + 1]);
            pr[k] = lo | (hi << 16);
        }
        *(uint4*)(out + (size_t)cam * HW * C + (size_t)(hw0 + hw) * C + cs) = r;
    }
}

// ---------------------------------------------------------------------------
// Pass 2: one 512-thread block per (d, hb): 336 c x full 120 wb.
// 8 waves x 15 wb; 3 cparts of 112 c looped inside. Per cpart each wave
// issues 16 asm global_load_dwordx4, consumes per-cam with counted vmcnt
// (never drains to 0 across the store phase). R6 lesson: launch_bounds
// (512,2) = 1 block/CU (21% occ); (512,4) = 2 blocks/CU. VGPR 72 fits the
// 128 budget.
// ---------------------------------------------------------------------------
#define LOADQ(dst, off, TF) \
    asm volatile("global_load_dwordx4 %0, %1, %2" \
                 : "=v"(dst) : "v"(off), "s"(TF))

#define VMWAIT(N) \
    do { asm volatile("s_waitcnt vmcnt(" #N ")" ::: "memory"); \
         __builtin_amdgcn_sched_barrier(0); } while (0)

#define LBAR() \
    do { asm volatile("s_waitcnt lgkmcnt(0)" ::: "memory"); \
         __builtin_amdgcn_sched_barrier(0); \
         __builtin_amdgcn_s_barrier(); } while (0)

#define ISSUE16() \
    do { \
        _Pragma("unroll") \
        for (int cam = 0; cam < 4; ++cam) { \
            _Pragma("unroll") \
            for (int wbi = 0; wbi < 4; ++wbi) { \
                LOADQ(q[cam][wbi], voff[cam][wbi], tfeat); \
                voff[cam][wbi] += 224u; \
            } \
        } \
    } while (0)

#define FMACAM(cam, NW, OP) \
    do { \
        VMWAIT(NW); \
        _Pragma("unroll") \
        for (int wbi = 0; wbi < 4; ++wbi) { \
            const float w = s_wgt[cam][wbc[wbi]]; \
            const u32x4 v = q[cam][wbi]; \
            acc[wbi][0] OP w * __uint_as_float(v[0] << 16); \
            acc[wbi][1] OP w * __uint_as_float(v[0] & 0xffff0000u); \
            acc[wbi][2] OP w * __uint_as_float(v[1] << 16); \
            acc[wbi][3] OP w * __uint_as_float(v[1] & 0xffff0000u); \
            acc[wbi][4] OP w * __uint_as_float(v[2] << 16); \
            acc[wbi][5] OP w * __uint_as_float(v[2] & 0xffff0000u); \
            acc[wbi][6] OP w * __uint_as_float(v[3] << 16); \
            acc[wbi][7] OP w * __uint_as_float(v[3] & 0xffff0000u); \
        } \
    } while (0)

__global__ __launch_bounds__(512, 4)
void vp_gather_bf16(const unsigned short* __restrict__ tfeat,
                    const int* __restrict__ pu, const int* __restrict__ pv,
                    const int* __restrict__ pvalid,
                    const float* __restrict__ pdens,
                    float* __restrict__ out) {
    __shared__ int   s_off[NCAM][WB];
    __shared__ float s_wgt[NCAM][WB];
    __shared__ float s_acc[56][121];

    const int d   = blockIdx.x / HB;
    const int hb  = blockIdx.x % HB;
    const int tid = threadIdx.x;

    if (tid < NCAM * WB) {
        const int cam = tid / WB, wb = tid % WB;
        const size_t pidx = ((size_t)(cam * D + d) * HB + hb) * WB + wb;
        s_wgt[cam][wb] = pvalid[pidx] ? pdens[pidx] : 0.0f;
        s_off[cam][wb] = cam * (HW * C) + (pv[pidx] * W + pu[pidx]) * C;
    }
    __syncthreads();

    const int wave  = tid >> 6;                // 0..7, owns wb [wave*15, +15)
    const int lane  = tid & 63;
    const int cq    = lane & 15;               // active < 14
    const int wbsub = lane >> 4;               // 0..3
    const bool cact = (cq < 14);
    const int coff  = (cact ? cq : 13) * 8;    // c-octet element offset

    int wbc[4];
#pragma unroll
    for (int wbi = 0; wbi < 4; ++wbi) {
        const int wbl = wbsub + 4 * wbi;       // active < 15
        wbc[wbi] = wave * 15 + (wbl < 15 ? wbl : 14);
    }

    unsigned voff[4][4];                        // byte offsets into tfeat
#pragma unroll
    for (int cam = 0; cam < 4; ++cam)
#pragma unroll
        for (int wbi = 0; wbi < 4; ++wbi)
            voff[cam][wbi] = (unsigned)(s_off[cam][wbc[wbi]] + coff) * 2u;

    u32x4 q[4][4];
    float acc[4][8];

    // dump acc -> LDS and sweep-store, two halves of 56 c-rows each.
    auto dumpstore = [&](int cp) {
#pragma unroll
        for (int half = 0; half < 2; ++half) {
            if (cact && cq >= half * 7 && cq < half * 7 + 7) {
                const int rbase = (cq - half * 7) * 8;
#pragma unroll
                for (int wbi = 0; wbi < 4; ++wbi) {
                    const int wbl = wbsub + 4 * wbi;
                    if (wbl < 15) {
#pragma unroll
                        for (int j = 0; j < 8; ++j)
                            s_acc[rbase + j][wave * 15 + wbl] = acc[wbi][j];
                    }
                }
            }
            LBAR();
            const int wp = tid & 63;           // active < 60
            const int rb = tid >> 6;           // 0..7
            if (wp < 60) {
#pragma unroll
                for (int k = 0; k < 7; ++k) {
                    const int r = rb + 8 * k;
                    const int c = cp * 112 + half * 56 + r;
                    float2 v;
                    v.x = s_acc[r][wp * 2 + 0];
                    v.y = s_acc[r][wp * 2 + 1];
                    *(float2*)(out + (((size_t)d * C + c) * HB + hb) * WB +
                               wp * 2) = v;
                }
            }
            LBAR();
        }
    };

    ISSUE16();                                  // cp0 loads in flight
    // ---- cp0: no prior stores outstanding -> waits 12/8/4/0
    FMACAM(0, 12, =);
    FMACAM(1, 8, +=);
    FMACAM(2, 4, +=);
    FMACAM(3, 0, +=);
    ISSUE16();                                  // cp1 loads (before stores)
    dumpstore(0);                               // 14 stores join the queue
    // ---- cp1: 16 loads oldest, 14 stores newer -> waits 26/22/18/14
    FMACAM(0, 26, =);
    FMACAM(1, 22, +=);
    FMACAM(2, 18, +=);
    FMACAM(3, 14, +=);
    ISSUE16();                                  // cp2 loads
    dumpstore(1);
    // ---- cp2
    FMACAM(0, 26, =);
    FMACAM(1, 22, +=);
    FMACAM(2, 18, +=);
    FMACAM(3, 14, +=);
    dumpstore(2);
}

extern "C" void kernel_launch(void* const* d_in, const int* in_sizes, int n_in,
                              void* d_out, int out_size, void* d_ws,
                              size_t ws_size, hipStream_t stream) {
    const float* feat  = (const float*)d_in[0];
    const int* pu      = (const int*)d_in[1];
    const int* pv      = (const int*)d_in[2];
    const int* pvalid  = (const int*)d_in[3];
    const float* pdens = (const float*)d_in[4];
    float* out         = (float*)d_out;

    unsigned short* tfeat = (unsigned short*)d_ws;   // 45.4 MB

    dim3 tgrid(HW / 64, (C + 31) / 32, NCAM);
    vp_transpose_bf16<<<tgrid, 256, 0, stream>>>(feat, tfeat);

    vp_gather_bf16<<<D * HB, 512, 0, stream>>>(tfeat, pu, pv, pvalid, pdens,
                                               out);
}